// Round 9
// baseline (20.480 us; speedup 1.0000x reference)
//
#include <hip/hip_runtime.h>

#define B 4
#define NQ 512
#define NK 512
#define D 128
#define H 32
#define G 4                              // queries per attend block
#define PS 2.8853900817779268f           // 2*log2(e)

__device__ __forceinline__ float rcp_f(float x)  { return __builtin_amdgcn_rcpf(x); }
__device__ __forceinline__ float exp2_f(float x) { return __builtin_amdgcn_exp2f(x); }

__device__ __forceinline__ void fma4(float4& a, const float4& v, float s) {
    a.x = fmaf(s, v.x, a.x);
    a.y = fmaf(s, v.y, a.y);
    a.z = fmaf(s, v.z, a.z);
    a.w = fmaf(s, v.w, a.w);
}

// Ek[b][h][k] = exp2(PS*(keys[b,k,:].Wk[:,h] + b1[h]))   (transposed)
// eq[b][q][h] = exp2(PS*(queries[b,q,:].Wq[:,h]))
__global__ __launch_bounds__(256) void proj_kernel(
    const float* __restrict__ keys, const float* __restrict__ queries,
    const float* __restrict__ Wk, const float* __restrict__ Wq,
    const float* __restrict__ b1,
    float* __restrict__ Ek, float* __restrict__ eq)
{
    __shared__ float xs[8][D];
    const int tid = threadIdx.x;
    const int r0 = blockIdx.x * 8;
    const bool is_q = (r0 >= B * NK);
    const float* __restrict__ X = is_q ? (queries + (size_t)(r0 - B * NK) * D)
                                       : (keys + (size_t)r0 * D);
    const float* __restrict__ W = is_q ? Wq : Wk;

    reinterpret_cast<float4*>(&xs[0][0])[tid] =
        reinterpret_cast<const float4*>(X)[tid];
    __syncthreads();

    const int lr = tid >> 5;
    const int h  = tid & 31;
    float a0 = 0.f, a1 = 0.f, a2 = 0.f, a3 = 0.f;
    const float4* x4 = reinterpret_cast<const float4*>(&xs[lr][0]);
    #pragma unroll
    for (int i = 0; i < D / 4; ++i) {
        float4 v = x4[i];
        a0 = fmaf(v.x, W[(4 * i + 0) * H + h], a0);
        a1 = fmaf(v.y, W[(4 * i + 1) * H + h], a1);
        a2 = fmaf(v.z, W[(4 * i + 2) * H + h], a2);
        a3 = fmaf(v.w, W[(4 * i + 3) * H + h], a3);
    }
    float acc = (a0 + a1) + (a2 + a3);
    if (is_q) {
        const int rq = r0 - B * NK + lr;
        eq[(size_t)rq * H + h] = exp2_f(acc * PS);
    } else {
        const int r = r0 + lr;
        const int b = r >> 9;
        const int k = r & (NK - 1);
        Ek[((size_t)b * H + h) * NK + k] = exp2_f((acc + b1[h]) * PS);
    }
}

// One block per (b, G=4 queries). 512 threads.
// Phase 1: thread tid owns key k=tid; reads Ek column (coalesced b32 global,
//          each element delivered ONCE), computes full logits for 4 queries in
//          registers. eq/w2 uniforms -> scalar loads (SMEM pipe).
// Softmax: no cross-lane gather needed; block sum-reduce only (no max pass:
//          |exponent| <= 2log2e*sum|w2| ~ 16.3, fp32-safe).
// Phase 2: thread (dg 0..31, kp 0..15): 32 keys, 4 d's, 4 queries.
__global__ __launch_bounds__(512) void attend_kernel(
    const float* __restrict__ keys,
    const float* __restrict__ Ek,     // [B][H][NK]
    const float* __restrict__ eq,     // [B][NQ][H]
    const float* __restrict__ w2,
    float* __restrict__ outp)
{
    __shared__ float exw[NK][G];      // 8 KB   normalized weights, [k][g]
    __shared__ float red[8][G];       // wave partial sums
    __shared__ float accm[16][G][D];  // 32 KB  context partials

    const int tid = threadIdx.x;
    const int b   = blockIdx.x >> 7;
    const int q0  = (blockIdx.x & 127) * G;

    // ---- phase 1: logits for key k = tid, queries q0..q0+3
    float acc0 = 0.f, acc1 = 0.f, acc2 = 0.f, acc3 = 0.f;
    const float* Ekc = Ek + (size_t)b * H * NK + tid;      // column base (per-lane)
    const float* eqb = eq + ((size_t)b * NQ + q0) * H;     // uniform base -> s_load
    #pragma unroll
    for (int h = 0; h < H; ++h) {
        const float ekv = Ekc[h * NK];        // coalesced 256B wave load
        const float w2h = w2[h];              // scalar load
        const float ev0 = eqb[0 * H + h];     // scalar loads
        const float ev1 = eqb[1 * H + h];
        const float ev2 = eqb[2 * H + h];
        const float ev3 = eqb[3 * H + h];
        acc0 = fmaf(w2h, rcp_f(fmaf(ev0, ekv, 1.f)), acc0);
        acc1 = fmaf(w2h, rcp_f(fmaf(ev1, ekv, 1.f)), acc1);
        acc2 = fmaf(w2h, rcp_f(fmaf(ev2, ekv, 1.f)), acc2);
        acc3 = fmaf(w2h, rcp_f(fmaf(ev3, ekv, 1.f)), acc3);
    }
    // exponent = -PS * acc  (constant term dropped; softmax shift-invariant)
    float e0 = exp2_f(-PS * acc0);
    float e1 = exp2_f(-PS * acc1);
    float e2 = exp2_f(-PS * acc2);
    float e3 = exp2_f(-PS * acc3);

    // ---- block sum over k: wave shuffle + LDS cross-wave
    float s0 = e0, s1 = e1, s2 = e2, s3 = e3;
    #pragma unroll
    for (int off = 32; off; off >>= 1) {
        s0 += __shfl_xor(s0, off);
        s1 += __shfl_xor(s1, off);
        s2 += __shfl_xor(s2, off);
        s3 += __shfl_xor(s3, off);
    }
    if ((tid & 63) == 0)
        *reinterpret_cast<float4*>(&red[tid >> 6][0]) = float4{s0, s1, s2, s3};
    __syncthreads();
    float4 sum = {0.f, 0.f, 0.f, 0.f};
    #pragma unroll
    for (int p = 0; p < 8; ++p) {
        const float4 v = *reinterpret_cast<const float4*>(&red[p][0]);  // broadcast
        sum.x += v.x; sum.y += v.y; sum.z += v.z; sum.w += v.w;
    }
    *reinterpret_cast<float4*>(&exw[tid][0]) =
        float4{e0 * rcp_f(sum.x), e1 * rcp_f(sum.y),
               e2 * rcp_f(sum.z), e3 * rcp_f(sum.w)};
    __syncthreads();

    // ---- phase 2: context. thread (dg, kp): 32 keys, 4 d's, 4 queries.
    const int dg = tid & 31;
    const int kp = tid >> 5;
    const float4* k4 = reinterpret_cast<const float4*>(
        keys + ((size_t)b * NK + kp * 32) * D) + dg;
    float4 a0 = {0,0,0,0}, a1 = a0, a2 = a0, a3 = a0;
    #pragma unroll 4
    for (int kk = 0; kk < 32; ++kk) {
        const float4 ev = *reinterpret_cast<const float4*>(&exw[kp * 32 + kk][0]); // broadcast
        const float4 kv = k4[(size_t)kk * (D / 4)];
        fma4(a0, kv, ev.x);
        fma4(a1, kv, ev.y);
        fma4(a2, kv, ev.z);
        fma4(a3, kv, ev.w);
    }
    *reinterpret_cast<float4*>(&accm[kp][0][4 * dg]) = a0;
    *reinterpret_cast<float4*>(&accm[kp][1][4 * dg]) = a1;
    *reinterpret_cast<float4*>(&accm[kp][2][4 * dg]) = a2;
    *reinterpret_cast<float4*>(&accm[kp][3][4 * dg]) = a3;
    __syncthreads();

    // ---- reduce 16 partitions; thread t -> output (g,d)
    const int g = tid >> 7;
    const int d = tid & 127;
    float r = 0.f;
    #pragma unroll
    for (int p = 0; p < 16; ++p) r += accm[p][g][d];
    outp[((size_t)b * NQ + q0 + g) * D + d] = r;
}

extern "C" void kernel_launch(void* const* d_in, const int* in_sizes, int n_in,
                              void* d_out, int out_size, void* d_ws, size_t ws_size,
                              hipStream_t stream) {
    const float* keys    = (const float*)d_in[0];
    const float* queries = (const float*)d_in[1];
    const float* Wk      = (const float*)d_in[2];
    const float* Wq      = (const float*)d_in[3];
    const float* b1      = (const float*)d_in[4];
    const float* w2      = (const float*)d_in[5];
    // d_in[6] = b2: dropped (softmax shift-invariant)
    float* out = (float*)d_out;

    float* Ek = (float*)d_ws;                    // B*H*NK floats (transposed)
    float* eq = Ek + (size_t)B * H * NK;         // B*NQ*H floats

    const int proj_blocks = (B * NK + B * NQ) / 8;   // 512
    proj_kernel<<<proj_blocks, 256, 0, stream>>>(keys, queries, Wk, Wq, b1, Ek, eq);
    attend_kernel<<<B * NQ / G, 512, 0, stream>>>(keys, Ek, eq, w2, out);
}